// Round 25
// baseline (98.683 us; speedup 1.0000x reference)
//
#include <hip/hip_runtime.h>
#include <hip/hip_bf16.h>

// Problem constants
constexpr int BB  = 2;
constexpr int CHN = 256;
constexpr int HH  = 80;
constexpr int WW  = 80;
constexpr int EE  = 64;
constexpr int HO  = 160;
constexpr int WO  = 160;

// Workspace layout (float offsets)
constexpr int OFF_WT_EN = 0;                    // BF bf16 B-frags of w1_en (16384 ushort)
constexpr int OFF_WT_DE = 16384;                // BF_DE bf16 B-frags of w1_de (16384 ushort) + BG gate frags (4096 ushort)
constexpr int OFF_WC    = 32768;                // [64][3][3][25] conv2_k transposed
constexpr int OFF_CES   = 47168;                // [B][4][162][162][16] padded+scrambled ce
constexpr int CES_SZ    = 2 * 4 * 162 * 162 * 16;   // 3,359,232
constexpr int OFF_CDG   = OFF_CES + CES_SZ;     // [B][82][82][64] padded cd
constexpr int CDG_SZ    = 2 * 82 * 82 * 64;     // 860,672
constexpr int OFF_GATE  = OFF_CDG + CDG_SZ;     // [B][80][80]
constexpr int OFF_KERN  = OFF_GATE + 2 * 80 * 80;   // [B][80][80][25][4] softmaxed (o-major, q-minor!)

using bf16x8 = __attribute__((ext_vector_type(8))) short;
using f32x4  = __attribute__((ext_vector_type(4))) float;

// X-macro: apply F to 0..24 (forces compile-time indices -> registers; rule #20)
#define REP25(F) F(0) F(1) F(2) F(3) F(4) F(5) F(6) F(7) F(8) F(9) F(10) F(11) \
                 F(12) F(13) F(14) F(15) F(16) F(17) F(18) F(19) F(20) F(21) F(22) F(23) F(24)

// ---------------------------------------------------------------------------
// prep (merged): all weight transforms + both pad-ring zero-fills.
// ---------------------------------------------------------------------------
__global__ __launch_bounds__(256) void fade_prep(
    const float* __restrict__ w1_en, const float* __restrict__ w1_de,
    const float* __restrict__ gate_w, const float* __restrict__ conv2_k,
    float* __restrict__ ws, float* __restrict__ ces, float* __restrict__ cdg) {
  int idx = blockIdx.x * 256 + threadIdx.x;
  if (idx < 16384) {
    int j = idx & 7, l = (idx >> 3) & 63, et = (idx >> 9) & 3, ks = idx >> 11;
    int cc = ks * 32 + (l >> 4) * 8 + j;
    int ee = et * 16 + (l & 15);
    unsigned u = __float_as_uint(w1_en[ee * CHN + cc]);
    u = (u + 0x7FFFu + ((u >> 16) & 1u)) >> 16;   // RNE to bf16
    ((unsigned short*)(ws + OFF_WT_EN))[idx] = (unsigned short)u;
    unsigned v = __float_as_uint(w1_de[ee * CHN + cc]);
    v = (v + 0x7FFFu + ((v >> 16) & 1u)) >> 16;
    ((unsigned short*)(ws + OFF_WT_DE))[idx] = (unsigned short)v;
  }
  if (idx < 4096) {
    // BG: gate fragment, col 0 = gate_w, other cols 0. ks = idx>>9 (0..7)
    int j = idx & 7, l = (idx >> 3) & 63, ks = idx >> 9;
    int cc = ks * 32 + (l >> 4) * 8 + j;
    unsigned short r = 0;
    if ((l & 15) == 0) {
      unsigned u = __float_as_uint(gate_w[cc]);
      u = (u + 0x7FFFu + ((u >> 16) & 1u)) >> 16;
      r = (unsigned short)u;
    }
    ((unsigned short*)(ws + OFF_WT_DE))[16384 + idx] = r;
  }
  if (idx < 14400) {
    int e = idx / 225, rem = idx % 225, t = rem / 25, o = rem % 25;
    ws[OFF_WC + idx] = conv2_k[(o * EE + e) * 9 + t];
  }
  if (idx < 82432) {
    int e4 = idx & 3;
    int rest = idx >> 2;
    int posb = rest % 644;
    int rest2 = rest / 644;
    int q = rest2 & 3, b = rest2 >> 2;
    int yy, xx;
    if (posb < 162)      { yy = 0;   xx = posb; }
    else if (posb < 324) { yy = 161; xx = posb - 162; }
    else if (posb < 484) { xx = 0;   yy = posb - 324 + 1; }
    else                 { xx = 161; yy = posb - 484 + 1; }
    float4 z = make_float4(0.f, 0.f, 0.f, 0.f);
    *(float4*)(ces + ((((size_t)b * 4 + q) * 162 + yy) * 162 + xx) * 16 + e4 * 4) = z;
  }
  if (idx < 10368) {
    // cdg pad ring: 324 cells/batch x 16 float4
    int e4 = idx & 15;
    int rest = idx >> 4;
    int cell = rest % 324, b = rest / 324;
    int yy, xx;
    if (cell < 82)       { yy = 0;  xx = cell; }
    else if (cell < 164) { yy = 81; xx = cell - 82; }
    else if (cell < 244) { xx = 0;  yy = cell - 164 + 1; }
    else                 { xx = 81; yy = cell - 244 + 1; }
    float4 z = make_float4(0.f, 0.f, 0.f, 0.f);
    *(float4*)(cdg + (((size_t)b * 82 + yy) * 82 + xx) * 64 + e4 * 4) = z;
  }
}

// ---------------------------------------------------------------------------
// conv1 (r24 win): BOTH 1x1 convs via bf16 MFMA, double-buffered LDS staging.
//   blocks [0,800):    ce = 1x1(en) -> scrambled ce_s interior
//   blocks [800,1000): cd = 1x1(de) -> cdg interior, + gate via a 5th MFMA
// ---------------------------------------------------------------------------
__global__ __launch_bounds__(256) void fade_conv1(
    const float* __restrict__ en, const float* __restrict__ b1_en,
    const unsigned short* __restrict__ BFu, float* __restrict__ ces,
    const float* __restrict__ de, const float* __restrict__ gate_b,
    const unsigned short* __restrict__ BFDu,
    float* __restrict__ cdg, float* __restrict__ gateo) {
  __shared__ float buf[2][32][65];
  int bi = blockIdx.x;
  int tid = threadIdx.x;
  int lane = tid & 63;
  int w = __builtin_amdgcn_readfirstlane(tid >> 6);   // 0..3
  int l15 = lane & 15, lg = lane >> 4;
  int cg = tid >> 6, po = tid & 63;

  if (bi < 800) {
    // ---------------- en path ----------------
    int b = bi / 400;
    int pos0 = (bi % 400) * 64;       // within batch plane (25600)
    const float* ep = en + (size_t)b * CHN * 25600 + pos0;
    const bf16x8* BFF = (const bf16x8*)BFu;

    f32x4 acc0, acc1, acc2, acc3;
    { float bv = b1_en[l15];      acc0 = (f32x4){bv, bv, bv, bv}; }
    { float bv = b1_en[16 + l15]; acc1 = (f32x4){bv, bv, bv, bv}; }
    { float bv = b1_en[32 + l15]; acc2 = (f32x4){bv, bv, bv, bv}; }
    { float bv = b1_en[48 + l15]; acc3 = (f32x4){bv, bv, bv, bv}; }

#pragma unroll
    for (int i = 0; i < 8; ++i) {
      int c = i * 4 + cg;
      buf[0][c][po] = ep[(size_t)c * 25600 + po];
    }
    __syncthreads();

    for (int ks = 0; ks < 8; ++ks) {
      int p = ks & 1;
      if (ks < 7) {
#pragma unroll
        for (int i = 0; i < 8; ++i) {
          int c = i * 4 + cg;
          buf[p ^ 1][c][po] = ep[(size_t)((ks + 1) * 32 + c) * 25600 + po];
        }
      }
      bf16x8 av;
#define LDA_(j) { unsigned u = __float_as_uint(buf[p][lg * 8 + (j)][w * 16 + l15]); \
      u = (u + 0x7FFFu + ((u >> 16) & 1u)) >> 16; av[(j)] = (short)u; }
      LDA_(0) LDA_(1) LDA_(2) LDA_(3) LDA_(4) LDA_(5) LDA_(6) LDA_(7)
#undef LDA_
      const bf16x8* bp = BFF + ks * 256 + lane;
      bf16x8 b0 = bp[0], b1 = bp[64], b2 = bp[128], b3 = bp[192];
      acc0 = __builtin_amdgcn_mfma_f32_16x16x32_bf16(av, b0, acc0, 0, 0, 0);
      acc1 = __builtin_amdgcn_mfma_f32_16x16x32_bf16(av, b1, acc1, 0, 0, 0);
      acc2 = __builtin_amdgcn_mfma_f32_16x16x32_bf16(av, b2, acc2, 0, 0, 0);
      acc3 = __builtin_amdgcn_mfma_f32_16x16x32_bf16(av, b3, acc3, 0, 0, 0);
      __syncthreads();
    }

    constexpr size_t QSTR = (size_t)162 * 162 * 16;
    float* cb = ces + (size_t)b * 4 * QSTR;
    int pbase = pos0 + w * 16 + lg * 4;
    int q = l15 & 3;
#define WR_(r) { int p2 = pbase + (r); int y = p2 / 160, x = p2 - y * 160; \
      size_t sb = (size_t)q * QSTR + (size_t)((y + 1) * 162 + (x + 1)) * 16 + (l15 >> 2); \
      cb[sb +  0] = acc0[(r)]; \
      cb[sb +  4] = acc1[(r)]; \
      cb[sb +  8] = acc2[(r)]; \
      cb[sb + 12] = acc3[(r)]; }
    WR_(0) WR_(1) WR_(2) WR_(3)
#undef WR_
  } else {
    // ---------------- de path (MFMA + gate column) ----------------
    int bj = bi - 800;
    int b = bj / 100;
    int pos0 = (bj % 100) * 64;       // within de plane (6400)
    const float* dp = de + (size_t)b * CHN * 6400 + pos0;
    const bf16x8* BFD = (const bf16x8*)BFDu;
    const bf16x8* BG  = (const bf16x8*)(BFDu + 16384);

    f32x4 acc0 = {0.f, 0.f, 0.f, 0.f}, acc1 = acc0, acc2 = acc0, acc3 = acc0;
    f32x4 accg;
    { float gb = gate_b[0]; accg = (f32x4){gb, gb, gb, gb}; }

#pragma unroll
    for (int i = 0; i < 8; ++i) {
      int c = i * 4 + cg;
      buf[0][c][po] = dp[(size_t)c * 6400 + po];
    }
    __syncthreads();

    for (int ks = 0; ks < 8; ++ks) {
      int p = ks & 1;
      if (ks < 7) {
#pragma unroll
        for (int i = 0; i < 8; ++i) {
          int c = i * 4 + cg;
          buf[p ^ 1][c][po] = dp[(size_t)((ks + 1) * 32 + c) * 6400 + po];
        }
      }
      bf16x8 av;
#define LDB_(j) { unsigned u = __float_as_uint(buf[p][lg * 8 + (j)][w * 16 + l15]); \
      u = (u + 0x7FFFu + ((u >> 16) & 1u)) >> 16; av[(j)] = (short)u; }
      LDB_(0) LDB_(1) LDB_(2) LDB_(3) LDB_(4) LDB_(5) LDB_(6) LDB_(7)
#undef LDB_
      const bf16x8* bp = BFD + ks * 256 + lane;
      bf16x8 b0 = bp[0], b1 = bp[64], b2 = bp[128], b3 = bp[192];
      bf16x8 bg = BG[ks * 64 + lane];
      acc0 = __builtin_amdgcn_mfma_f32_16x16x32_bf16(av, b0, acc0, 0, 0, 0);
      acc1 = __builtin_amdgcn_mfma_f32_16x16x32_bf16(av, b1, acc1, 0, 0, 0);
      acc2 = __builtin_amdgcn_mfma_f32_16x16x32_bf16(av, b2, acc2, 0, 0, 0);
      acc3 = __builtin_amdgcn_mfma_f32_16x16x32_bf16(av, b3, acc3, 0, 0, 0);
      accg = __builtin_amdgcn_mfma_f32_16x16x32_bf16(av, bg, accg, 0, 0, 0);
      __syncthreads();
    }

    float* cdb = cdg + (size_t)b * 82 * 82 * 64;
    int pbase = pos0 + w * 16 + lg * 4;
#define WRD_(r) { int p2 = pbase + (r); int y = p2 / 80, x = p2 - y * 80; \
      size_t sb = (size_t)((y + 1) * 82 + (x + 1)) * 64 + l15; \
      cdb[sb +  0] = acc0[(r)]; \
      cdb[sb + 16] = acc1[(r)]; \
      cdb[sb + 32] = acc2[(r)]; \
      cdb[sb + 48] = acc3[(r)]; \
      if (l15 == 0) gateo[(size_t)b * 6400 + p2] = 1.f / (1.f + __expf(-accg[(r)])); }
    WRD_(0) WRD_(1) WRD_(2) WRD_(3)
#undef WRD_
  }
}

// ---------------------------------------------------------------------------
// kern: MERGED k_de+k_en tap loop (r13 win) + 2-stage pipeline (r21 win).
// ---------------------------------------------------------------------------
__global__ __launch_bounds__(512) void fade_kern(
    const float* __restrict__ WC, const float* __restrict__ CES,
    const float* __restrict__ CDG, const float* __restrict__ conv2_b,
    float* __restrict__ KERN) {
  __shared__ float part[64 * 101];   // [row][(wv&3)*25+o], stride 101 (conflict-free)
  __shared__ float score[64 * 27];
  int bi = blockIdx.x;
  int b = bi / 400, t = bi % 400;
  int th0 = (t / 20) * 4, tw0 = (t % 20) * 4;
  int tid = threadIdx.x;
  int lane = tid & 63;
  int wv = __builtin_amdgcn_readfirstlane(tid >> 6);   // 0..7 K-slice
  int cell = lane >> 2, q = lane & 3;
  int h = th0 + (cell >> 2), w = tw0 + (cell & 3);

#define KDECL_(i) float a##i = 0.f;
  REP25(KDECL_)

#define KCH(val, base) { const float vv = (val); const float* wb = (base); \
    REP25(KFMA_) }
#define KFMA_(i) a##i = fmaf(vv, wb[(i)], a##i);

  {
    int g = wv >> 1;
    const int pt = (g < 2) ? 1 : 0;
    const int pl = (g & 1) ? 0 : 1;
    const int eb = 8 * (wv & 1);
    const float* cpd_base = CDG + (((size_t)b * 82 + h) * 82 + w) * 64 + 8 * wv;
    const float* cpe_base = CES + ((((size_t)b * 4 + q) * 162 + (2 * h + 1 - pt)) * 162 +
                                   (2 * w + 1 - pl)) * 16 + eb;
    float4 u0 = *(const float4*)(cpd_base);
    float4 u1 = *(const float4*)(cpd_base + 4);
    float4 v0 = *(const float4*)(cpe_base);
    float4 v1 = *(const float4*)(cpe_base + 4);
    for (int d = 0; d < 9; ++d) {
      float4 nu0, nu1, nv0, nv1;
      if (d < 8) {
        int dn = d + 1;
        int di = dn / 3, dj = dn - 3 * di;       // wave-uniform SALU
        const float* cpd = cpd_base + (di * 82 + dj) * 64;
        const float* cpe = cpe_base + (di * 162 + dj) * 16;
        nu0 = *(const float4*)(cpd);
        nu1 = *(const float4*)(cpd + 4);
        nv0 = *(const float4*)(cpe);
        nv1 = *(const float4*)(cpe + 4);
      }
      const float* wt = WC + (8 * wv * 9 + d) * 25;
      KCH(u0.x + v0.x, wt)         KCH(u0.y + v0.y, wt + 225)
      KCH(u0.z + v0.z, wt + 450)   KCH(u0.w + v0.w, wt + 675)
      KCH(u1.x + v1.x, wt + 900)   KCH(u1.y + v1.y, wt + 1125)
      KCH(u1.z + v1.z, wt + 1350)  KCH(u1.w + v1.w, wt + 1575)
      if (d < 8) { u0 = nu0; u1 = nu1; v0 = nv0; v1 = nv1; }
    }
  }

  {
    int pbase = lane * 101 + (wv & 3) * 25;
    if (wv < 4) {
#define KST_(i) part[pbase + (i)] = a##i;
      REP25(KST_)
    }
    __syncthreads();
    if (wv >= 4) {
#define KAD_(i) part[pbase + (i)] += a##i;
      REP25(KAD_)
    }
  }
  __syncthreads();

  {
    int row = tid & 63, sub = tid >> 6;
    int nO = (sub == 7) ? 4 : 3;
    for (int m = 0; m < nO; ++m) {
      int o = sub * 3 + m;
      float s = 0.f;
#pragma unroll
      for (int w4 = 0; w4 < 4; ++w4) s += part[row * 101 + w4 * 25 + o];
      score[row * 27 + o] = s + 2.f * conv2_b[o];   // bias in BOTH k_en and k_de
    }
  }
  __syncthreads();

  if (tid < 64) {
    int sbase = tid * 27;
#define SLD_(i) float s##i = score[sbase + (i)];
    REP25(SLD_)
    float mx = s0;
#define SMX_(i) mx = fmaxf(mx, s##i);
    REP25(SMX_)
    float sum = 0.f;
#define SEX_(i) s##i = __expf(s##i - mx); sum += s##i;
    REP25(SEX_)
    float inv = 1.f / sum;
    int cl = tid >> 2, qq = tid & 3;
    int hh = th0 + (cl >> 2), ww2 = tw0 + (cl & 3);
    float* kp = KERN + (size_t)(b * 6400 + hh * 80 + ww2) * 100;
#define SWR_(i) kp[(i) * 4 + qq] = s##i * inv;
    REP25(SWR_)
  }
}

// ---------------------------------------------------------------------------
// final (r25): CARAFE + gate blend, CHANNEL-CHUNK LOOP. r24 grid was 3200
// blocks = 8 blocks per tile, each re-staging the SAME tile's 12.8KB kern
// (41MB of L2/XCD re-reads + 8x setup). Now grid = 1600 (tile x chunk-pair);
// each block stages kern/gate ONCE and loops 2 channel-chunks, staging only
// sde per chunk. LDS unchanged (26.6KB); same arithmetic, same addresses.
// ---------------------------------------------------------------------------
__global__ __launch_bounds__(256) void fade_final(
    const float* __restrict__ en, const float* __restrict__ de,
    const float* __restrict__ KERN, const float* __restrict__ GATE,
    float* __restrict__ out) {
  __shared__ float sde[32 * 105];    // 32 channels x (8 rows x 13 cols pad)
  __shared__ float4 kled[25][33];    // [o][cell], pad 33 vs write conflicts
  int bi = blockIdx.x;
  int b = bi / 800, r = bi % 800;
  int t = r >> 2, cp = r & 3;        // tile t (0..199), chunk-pair cp (0..3)
  int th0 = (t / 10) * 4, tw0 = (t % 10) * 8;
  int tid = threadIdx.x;
  int sg = tid >> 5, cell = tid & 31;
  int chh = cell >> 3, cw = cell & 7;
  int h = th0 + chh, w = tw0 + cw;

  // stage kern ONCE: 800 float4 (32 cells x 25 o), coalesced (o fastest)
  for (int kk = tid; kk < 800; kk += 256) {
    int cl2 = kk / 25, o = kk % 25;
    int hc = th0 + (cl2 >> 3), wc = tw0 + (cl2 & 7);
    kled[o][cl2] = *((const float4*)(KERN + (size_t)(b * 6400 + hc * 80 + wc) * 100) + o);
  }
  float gv = GATE[((size_t)b * 80 + h) * 80 + w];
  float gv1 = 1.f - gv;

  for (int ci2 = 0; ci2 < 2; ++ci2) {
    int cc = cp * 2 + ci2;           // channel chunk 0..7
    __syncthreads();
    // stage de: channels cc*32 .. +32, rows th0-2..+5, cols tw0-2..+9
    for (int kk = tid; kk < 3072; kk += 256) {
      int ci = kk / 96, rem = kk % 96, rr = rem / 12, c2 = rem % 12;
      int dr = th0 - 2 + rr, dc = tw0 - 2 + c2;
      float v = 0.f;
      if (dr >= 0 && dr < HH && dc >= 0 && dc < WW)
        v = de[((size_t)(b * CHN + cc * 32 + ci) * HH + dr) * WW + dc];
      sde[ci * 105 + rr * 13 + c2] = v;
    }
    __syncthreads();

#pragma unroll
    for (int j = 0; j < 4; ++j) {
      int c = cc * 32 + sg * 4 + j;
      int sbase2 = (sg * 4 + j) * 105 + chh * 13 + cw;
#define FWD_(o) float w##o = sde[sbase2 + ((o) / 5) * 13 + ((o) % 5)];
      REP25(FWD_)
      float s00 = 0.f, s01 = 0.f, s10 = 0.f, s11 = 0.f;
#define FCF_(o) { float4 kv = kled[(o)][cell]; \
                  s00 = fmaf(w##o, kv.x, s00); s01 = fmaf(w##o, kv.y, s01); \
                  s10 = fmaf(w##o, kv.z, s10); s11 = fmaf(w##o, kv.w, s11); }
      REP25(FCF_)

      const float* ep = en + ((size_t)(b * CHN + c) * HO + 2 * h) * WO + 2 * w;
      float* op = out + ((size_t)(b * CHN + c) * HO + 2 * h) * WO + 2 * w;
      float2 e0 = *(const float2*)(ep);
      float2 e1 = *(const float2*)(ep + WO);
      float2 r0, r1;
      r0.x = fmaf(gv, e0.x, gv1 * s00);
      r0.y = fmaf(gv, e0.y, gv1 * s01);
      r1.x = fmaf(gv, e1.x, gv1 * s10);
      r1.y = fmaf(gv, e1.y, gv1 * s11);
      *(float2*)(op) = r0;
      *(float2*)(op + WO) = r1;
    }
  }
}

// ---------------------------------------------------------------------------
extern "C" void kernel_launch(void* const* d_in, const int* in_sizes, int n_in,
                              void* d_out, int out_size, void* d_ws, size_t ws_size,
                              hipStream_t stream) {
  const float* en      = (const float*)d_in[0];
  const float* de      = (const float*)d_in[1];
  const float* gate_w  = (const float*)d_in[2];
  const float* gate_b  = (const float*)d_in[3];
  const float* w1_en   = (const float*)d_in[4];
  const float* b1_en   = (const float*)d_in[5];
  const float* w1_de   = (const float*)d_in[6];
  const float* conv2_k = (const float*)d_in[7];
  const float* conv2_b = (const float*)d_in[8];
  float* ws  = (float*)d_ws;
  float* out = (float*)d_out;

  const unsigned short* bfu  = (const unsigned short*)(ws + OFF_WT_EN);
  const unsigned short* bfdu = (const unsigned short*)(ws + OFF_WT_DE);
  float* wc    = ws + OFF_WC;
  float* cesb  = ws + OFF_CES;
  float* cdgb  = ws + OFF_CDG;
  float* gateo = ws + OFF_GATE;
  float* kernb = ws + OFF_KERN;

  hipLaunchKernelGGL(fade_prep,   dim3(322),  dim3(256), 0, stream,
                     w1_en, w1_de, gate_w, conv2_k, ws, cesb, cdgb);
  hipLaunchKernelGGL(fade_conv1,  dim3(1000), dim3(256), 0, stream,
                     en, b1_en, bfu, cesb, de, gate_b, bfdu, cdgb, gateo);
  hipLaunchKernelGGL(fade_kern,   dim3(800),  dim3(512), 0, stream,
                     wc, cesb, cdgb, conv2_b, kernb);
  hipLaunchKernelGGL(fade_final,  dim3(1600), dim3(256), 0, stream,
                     en, de, kernb, gateo, out);
}

// Round 26
// 92.400 us; speedup vs baseline: 1.0680x; 1.0680x over previous
//
#include <hip/hip_runtime.h>
#include <hip/hip_bf16.h>

// Problem constants
constexpr int BB  = 2;
constexpr int CHN = 256;
constexpr int HH  = 80;
constexpr int WW  = 80;
constexpr int EE  = 64;
constexpr int HO  = 160;
constexpr int WO  = 160;

// Workspace layout (float offsets)
constexpr int OFF_WT_EN = 0;                    // BF bf16 B-frags of w1_en (16384 ushort)
constexpr int OFF_WT_DE = 16384;                // BF_DE bf16 B-frags of w1_de (16384 ushort) + BG gate frags (4096 ushort)
constexpr int OFF_WC    = 32768;                // [64][3][3][25] conv2_k transposed
constexpr int OFF_CES   = 47168;                // [B][4][162][162][16] padded+scrambled ce
constexpr int CES_SZ    = 2 * 4 * 162 * 162 * 16;   // 3,359,232
constexpr int OFF_CDG   = OFF_CES + CES_SZ;     // [B][82][82][64] padded cd
constexpr int CDG_SZ    = 2 * 82 * 82 * 64;     // 860,672
constexpr int OFF_GATE  = OFF_CDG + CDG_SZ;     // [B][80][80]
constexpr int OFF_KERN  = OFF_GATE + 2 * 80 * 80;   // [B][80][80][25][4] softmaxed (o-major, q-minor!)

using bf16x8 = __attribute__((ext_vector_type(8))) short;
using f32x4  = __attribute__((ext_vector_type(4))) float;

// X-macro: apply F to 0..24 (forces compile-time indices -> registers; rule #20)
#define REP25(F) F(0) F(1) F(2) F(3) F(4) F(5) F(6) F(7) F(8) F(9) F(10) F(11) \
                 F(12) F(13) F(14) F(15) F(16) F(17) F(18) F(19) F(20) F(21) F(22) F(23) F(24)

// ---------------------------------------------------------------------------
// prep (merged): all weight transforms + both pad-ring zero-fills.
// ---------------------------------------------------------------------------
__global__ __launch_bounds__(256) void fade_prep(
    const float* __restrict__ w1_en, const float* __restrict__ w1_de,
    const float* __restrict__ gate_w, const float* __restrict__ conv2_k,
    float* __restrict__ ws, float* __restrict__ ces, float* __restrict__ cdg) {
  int idx = blockIdx.x * 256 + threadIdx.x;
  if (idx < 16384) {
    int j = idx & 7, l = (idx >> 3) & 63, et = (idx >> 9) & 3, ks = idx >> 11;
    int cc = ks * 32 + (l >> 4) * 8 + j;
    int ee = et * 16 + (l & 15);
    unsigned u = __float_as_uint(w1_en[ee * CHN + cc]);
    u = (u + 0x7FFFu + ((u >> 16) & 1u)) >> 16;   // RNE to bf16
    ((unsigned short*)(ws + OFF_WT_EN))[idx] = (unsigned short)u;
    unsigned v = __float_as_uint(w1_de[ee * CHN + cc]);
    v = (v + 0x7FFFu + ((v >> 16) & 1u)) >> 16;
    ((unsigned short*)(ws + OFF_WT_DE))[idx] = (unsigned short)v;
  }
  if (idx < 4096) {
    // BG: gate fragment, col 0 = gate_w, other cols 0. ks = idx>>9 (0..7)
    int j = idx & 7, l = (idx >> 3) & 63, ks = idx >> 9;
    int cc = ks * 32 + (l >> 4) * 8 + j;
    unsigned short r = 0;
    if ((l & 15) == 0) {
      unsigned u = __float_as_uint(gate_w[cc]);
      u = (u + 0x7FFFu + ((u >> 16) & 1u)) >> 16;
      r = (unsigned short)u;
    }
    ((unsigned short*)(ws + OFF_WT_DE))[16384 + idx] = r;
  }
  if (idx < 14400) {
    int e = idx / 225, rem = idx % 225, t = rem / 25, o = rem % 25;
    ws[OFF_WC + idx] = conv2_k[(o * EE + e) * 9 + t];
  }
  if (idx < 82432) {
    int e4 = idx & 3;
    int rest = idx >> 2;
    int posb = rest % 644;
    int rest2 = rest / 644;
    int q = rest2 & 3, b = rest2 >> 2;
    int yy, xx;
    if (posb < 162)      { yy = 0;   xx = posb; }
    else if (posb < 324) { yy = 161; xx = posb - 162; }
    else if (posb < 484) { xx = 0;   yy = posb - 324 + 1; }
    else                 { xx = 161; yy = posb - 484 + 1; }
    float4 z = make_float4(0.f, 0.f, 0.f, 0.f);
    *(float4*)(ces + ((((size_t)b * 4 + q) * 162 + yy) * 162 + xx) * 16 + e4 * 4) = z;
  }
  if (idx < 10368) {
    // cdg pad ring: 324 cells/batch x 16 float4
    int e4 = idx & 15;
    int rest = idx >> 4;
    int cell = rest % 324, b = rest / 324;
    int yy, xx;
    if (cell < 82)       { yy = 0;  xx = cell; }
    else if (cell < 164) { yy = 81; xx = cell - 82; }
    else if (cell < 244) { xx = 0;  yy = cell - 164 + 1; }
    else                 { xx = 81; yy = cell - 244 + 1; }
    float4 z = make_float4(0.f, 0.f, 0.f, 0.f);
    *(float4*)(cdg + (((size_t)b * 82 + yy) * 82 + xx) * 64 + e4 * 4) = z;
  }
}

// ---------------------------------------------------------------------------
// conv1 (r24 win): BOTH 1x1 convs via bf16 MFMA, double-buffered LDS staging.
//   blocks [0,800):    ce = 1x1(en) -> scrambled ce_s interior
//   blocks [800,1000): cd = 1x1(de) -> cdg interior, + gate via a 5th MFMA
// ---------------------------------------------------------------------------
__global__ __launch_bounds__(256) void fade_conv1(
    const float* __restrict__ en, const float* __restrict__ b1_en,
    const unsigned short* __restrict__ BFu, float* __restrict__ ces,
    const float* __restrict__ de, const float* __restrict__ gate_b,
    const unsigned short* __restrict__ BFDu,
    float* __restrict__ cdg, float* __restrict__ gateo) {
  __shared__ float buf[2][32][65];
  int bi = blockIdx.x;
  int tid = threadIdx.x;
  int lane = tid & 63;
  int w = __builtin_amdgcn_readfirstlane(tid >> 6);   // 0..3
  int l15 = lane & 15, lg = lane >> 4;
  int cg = tid >> 6, po = tid & 63;

  if (bi < 800) {
    // ---------------- en path ----------------
    int b = bi / 400;
    int pos0 = (bi % 400) * 64;       // within batch plane (25600)
    const float* ep = en + (size_t)b * CHN * 25600 + pos0;
    const bf16x8* BFF = (const bf16x8*)BFu;

    f32x4 acc0, acc1, acc2, acc3;
    { float bv = b1_en[l15];      acc0 = (f32x4){bv, bv, bv, bv}; }
    { float bv = b1_en[16 + l15]; acc1 = (f32x4){bv, bv, bv, bv}; }
    { float bv = b1_en[32 + l15]; acc2 = (f32x4){bv, bv, bv, bv}; }
    { float bv = b1_en[48 + l15]; acc3 = (f32x4){bv, bv, bv, bv}; }

#pragma unroll
    for (int i = 0; i < 8; ++i) {
      int c = i * 4 + cg;
      buf[0][c][po] = ep[(size_t)c * 25600 + po];
    }
    __syncthreads();

    for (int ks = 0; ks < 8; ++ks) {
      int p = ks & 1;
      if (ks < 7) {
#pragma unroll
        for (int i = 0; i < 8; ++i) {
          int c = i * 4 + cg;
          buf[p ^ 1][c][po] = ep[(size_t)((ks + 1) * 32 + c) * 25600 + po];
        }
      }
      bf16x8 av;
#define LDA_(j) { unsigned u = __float_as_uint(buf[p][lg * 8 + (j)][w * 16 + l15]); \
      u = (u + 0x7FFFu + ((u >> 16) & 1u)) >> 16; av[(j)] = (short)u; }
      LDA_(0) LDA_(1) LDA_(2) LDA_(3) LDA_(4) LDA_(5) LDA_(6) LDA_(7)
#undef LDA_
      const bf16x8* bp = BFF + ks * 256 + lane;
      bf16x8 b0 = bp[0], b1 = bp[64], b2 = bp[128], b3 = bp[192];
      acc0 = __builtin_amdgcn_mfma_f32_16x16x32_bf16(av, b0, acc0, 0, 0, 0);
      acc1 = __builtin_amdgcn_mfma_f32_16x16x32_bf16(av, b1, acc1, 0, 0, 0);
      acc2 = __builtin_amdgcn_mfma_f32_16x16x32_bf16(av, b2, acc2, 0, 0, 0);
      acc3 = __builtin_amdgcn_mfma_f32_16x16x32_bf16(av, b3, acc3, 0, 0, 0);
      __syncthreads();
    }

    constexpr size_t QSTR = (size_t)162 * 162 * 16;
    float* cb = ces + (size_t)b * 4 * QSTR;
    int pbase = pos0 + w * 16 + lg * 4;
    int q = l15 & 3;
#define WR_(r) { int p2 = pbase + (r); int y = p2 / 160, x = p2 - y * 160; \
      size_t sb = (size_t)q * QSTR + (size_t)((y + 1) * 162 + (x + 1)) * 16 + (l15 >> 2); \
      cb[sb +  0] = acc0[(r)]; \
      cb[sb +  4] = acc1[(r)]; \
      cb[sb +  8] = acc2[(r)]; \
      cb[sb + 12] = acc3[(r)]; }
    WR_(0) WR_(1) WR_(2) WR_(3)
#undef WR_
  } else {
    // ---------------- de path (MFMA + gate column) ----------------
    int bj = bi - 800;
    int b = bj / 100;
    int pos0 = (bj % 100) * 64;       // within de plane (6400)
    const float* dp = de + (size_t)b * CHN * 6400 + pos0;
    const bf16x8* BFD = (const bf16x8*)BFDu;
    const bf16x8* BG  = (const bf16x8*)(BFDu + 16384);

    f32x4 acc0 = {0.f, 0.f, 0.f, 0.f}, acc1 = acc0, acc2 = acc0, acc3 = acc0;
    f32x4 accg;
    { float gb = gate_b[0]; accg = (f32x4){gb, gb, gb, gb}; }

#pragma unroll
    for (int i = 0; i < 8; ++i) {
      int c = i * 4 + cg;
      buf[0][c][po] = dp[(size_t)c * 6400 + po];
    }
    __syncthreads();

    for (int ks = 0; ks < 8; ++ks) {
      int p = ks & 1;
      if (ks < 7) {
#pragma unroll
        for (int i = 0; i < 8; ++i) {
          int c = i * 4 + cg;
          buf[p ^ 1][c][po] = dp[(size_t)((ks + 1) * 32 + c) * 6400 + po];
        }
      }
      bf16x8 av;
#define LDB_(j) { unsigned u = __float_as_uint(buf[p][lg * 8 + (j)][w * 16 + l15]); \
      u = (u + 0x7FFFu + ((u >> 16) & 1u)) >> 16; av[(j)] = (short)u; }
      LDB_(0) LDB_(1) LDB_(2) LDB_(3) LDB_(4) LDB_(5) LDB_(6) LDB_(7)
#undef LDB_
      const bf16x8* bp = BFD + ks * 256 + lane;
      bf16x8 b0 = bp[0], b1 = bp[64], b2 = bp[128], b3 = bp[192];
      bf16x8 bg = BG[ks * 64 + lane];
      acc0 = __builtin_amdgcn_mfma_f32_16x16x32_bf16(av, b0, acc0, 0, 0, 0);
      acc1 = __builtin_amdgcn_mfma_f32_16x16x32_bf16(av, b1, acc1, 0, 0, 0);
      acc2 = __builtin_amdgcn_mfma_f32_16x16x32_bf16(av, b2, acc2, 0, 0, 0);
      acc3 = __builtin_amdgcn_mfma_f32_16x16x32_bf16(av, b3, acc3, 0, 0, 0);
      accg = __builtin_amdgcn_mfma_f32_16x16x32_bf16(av, bg, accg, 0, 0, 0);
      __syncthreads();
    }

    float* cdb = cdg + (size_t)b * 82 * 82 * 64;
    int pbase = pos0 + w * 16 + lg * 4;
#define WRD_(r) { int p2 = pbase + (r); int y = p2 / 80, x = p2 - y * 80; \
      size_t sb = (size_t)((y + 1) * 82 + (x + 1)) * 64 + l15; \
      cdb[sb +  0] = acc0[(r)]; \
      cdb[sb + 16] = acc1[(r)]; \
      cdb[sb + 32] = acc2[(r)]; \
      cdb[sb + 48] = acc3[(r)]; \
      if (l15 == 0) gateo[(size_t)b * 6400 + p2] = 1.f / (1.f + __expf(-accg[(r)])); }
    WRD_(0) WRD_(1) WRD_(2) WRD_(3)
#undef WRD_
  }
}

// ---------------------------------------------------------------------------
// kern: MERGED k_de+k_en tap loop (r13 win) + 2-stage pipeline (r21 win).
// ---------------------------------------------------------------------------
__global__ __launch_bounds__(512) void fade_kern(
    const float* __restrict__ WC, const float* __restrict__ CES,
    const float* __restrict__ CDG, const float* __restrict__ conv2_b,
    float* __restrict__ KERN) {
  __shared__ float part[64 * 101];   // [row][(wv&3)*25+o], stride 101 (conflict-free)
  __shared__ float score[64 * 27];
  int bi = blockIdx.x;
  int b = bi / 400, t = bi % 400;
  int th0 = (t / 20) * 4, tw0 = (t % 20) * 4;
  int tid = threadIdx.x;
  int lane = tid & 63;
  int wv = __builtin_amdgcn_readfirstlane(tid >> 6);   // 0..7 K-slice
  int cell = lane >> 2, q = lane & 3;
  int h = th0 + (cell >> 2), w = tw0 + (cell & 3);

#define KDECL_(i) float a##i = 0.f;
  REP25(KDECL_)

#define KCH(val, base) { const float vv = (val); const float* wb = (base); \
    REP25(KFMA_) }
#define KFMA_(i) a##i = fmaf(vv, wb[(i)], a##i);

  {
    int g = wv >> 1;
    const int pt = (g < 2) ? 1 : 0;
    const int pl = (g & 1) ? 0 : 1;
    const int eb = 8 * (wv & 1);
    const float* cpd_base = CDG + (((size_t)b * 82 + h) * 82 + w) * 64 + 8 * wv;
    const float* cpe_base = CES + ((((size_t)b * 4 + q) * 162 + (2 * h + 1 - pt)) * 162 +
                                   (2 * w + 1 - pl)) * 16 + eb;
    float4 u0 = *(const float4*)(cpd_base);
    float4 u1 = *(const float4*)(cpd_base + 4);
    float4 v0 = *(const float4*)(cpe_base);
    float4 v1 = *(const float4*)(cpe_base + 4);
    for (int d = 0; d < 9; ++d) {
      float4 nu0, nu1, nv0, nv1;
      if (d < 8) {
        int dn = d + 1;
        int di = dn / 3, dj = dn - 3 * di;       // wave-uniform SALU
        const float* cpd = cpd_base + (di * 82 + dj) * 64;
        const float* cpe = cpe_base + (di * 162 + dj) * 16;
        nu0 = *(const float4*)(cpd);
        nu1 = *(const float4*)(cpd + 4);
        nv0 = *(const float4*)(cpe);
        nv1 = *(const float4*)(cpe + 4);
      }
      const float* wt = WC + (8 * wv * 9 + d) * 25;
      KCH(u0.x + v0.x, wt)         KCH(u0.y + v0.y, wt + 225)
      KCH(u0.z + v0.z, wt + 450)   KCH(u0.w + v0.w, wt + 675)
      KCH(u1.x + v1.x, wt + 900)   KCH(u1.y + v1.y, wt + 1125)
      KCH(u1.z + v1.z, wt + 1350)  KCH(u1.w + v1.w, wt + 1575)
      if (d < 8) { u0 = nu0; u1 = nu1; v0 = nv0; v1 = nv1; }
    }
  }

  {
    int pbase = lane * 101 + (wv & 3) * 25;
    if (wv < 4) {
#define KST_(i) part[pbase + (i)] = a##i;
      REP25(KST_)
    }
    __syncthreads();
    if (wv >= 4) {
#define KAD_(i) part[pbase + (i)] += a##i;
      REP25(KAD_)
    }
  }
  __syncthreads();

  {
    int row = tid & 63, sub = tid >> 6;
    int nO = (sub == 7) ? 4 : 3;
    for (int m = 0; m < nO; ++m) {
      int o = sub * 3 + m;
      float s = 0.f;
#pragma unroll
      for (int w4 = 0; w4 < 4; ++w4) s += part[row * 101 + w4 * 25 + o];
      score[row * 27 + o] = s + 2.f * conv2_b[o];   // bias in BOTH k_en and k_de
    }
  }
  __syncthreads();

  if (tid < 64) {
    int sbase = tid * 27;
#define SLD_(i) float s##i = score[sbase + (i)];
    REP25(SLD_)
    float mx = s0;
#define SMX_(i) mx = fmaxf(mx, s##i);
    REP25(SMX_)
    float sum = 0.f;
#define SEX_(i) s##i = __expf(s##i - mx); sum += s##i;
    REP25(SEX_)
    float inv = 1.f / sum;
    int cl = tid >> 2, qq = tid & 3;
    int hh = th0 + (cl >> 2), ww2 = tw0 + (cl & 3);
    float* kp = KERN + (size_t)(b * 6400 + hh * 80 + ww2) * 100;
#define SWR_(i) kp[(i) * 4 + qq] = s##i * inv;
    REP25(SWR_)
  }
}

// ---------------------------------------------------------------------------
// final: CARAFE + gate blend, EXACT r24 structure (grid 3200 = tile x chunk,
// LDS kern staging). r25 lesson: the 8x/tile kern re-stagings were L2-HITS
// (FETCH stayed ~52MB); the chunk-pair restructure broke that co-residency
// (FETCH 74.8MB, final 43us) -- reverted.
// ---------------------------------------------------------------------------
__global__ __launch_bounds__(256) void fade_final(
    const float* __restrict__ en, const float* __restrict__ de,
    const float* __restrict__ KERN, const float* __restrict__ GATE,
    float* __restrict__ out) {
  __shared__ float sde[32 * 105];    // 32 channels x (8 rows x 13 cols pad)
  __shared__ float4 kled[25][33];    // [o][cell], pad 33 vs write conflicts
  int bi = blockIdx.x;
  int b = bi / 1600, r = bi % 1600;
  int t = r >> 3, cc = r & 7;
  int th0 = (t / 10) * 4, tw0 = (t % 10) * 8;
  int tid = threadIdx.x;
  int sg = tid >> 5, cell = tid & 31;
  int chh = cell >> 3, cw = cell & 7;
  int h = th0 + chh, w = tw0 + cw;

  // stage de: channels cc*32 .. +32, rows th0-2..+5, cols tw0-2..+9
  for (int kk = tid; kk < 3072; kk += 256) {
    int ci = kk / 96, rem = kk % 96, rr = rem / 12, c2 = rem % 12;
    int dr = th0 - 2 + rr, dc = tw0 - 2 + c2;
    float v = 0.f;
    if (dr >= 0 && dr < HH && dc >= 0 && dc < WW)
      v = de[((size_t)(b * CHN + cc * 32 + ci) * HH + dr) * WW + dc];
    sde[ci * 105 + rr * 13 + c2] = v;
  }
  // stage kern: 800 float4 (32 cells x 25 o), coalesced (o fastest)
  for (int kk = tid; kk < 800; kk += 256) {
    int cl2 = kk / 25, o = kk % 25;
    int hc = th0 + (cl2 >> 3), wc = tw0 + (cl2 & 7);
    kled[o][cl2] = *((const float4*)(KERN + (size_t)(b * 6400 + hc * 80 + wc) * 100) + o);
  }
  __syncthreads();

  float gv = GATE[((size_t)b * 80 + h) * 80 + w];
  float gv1 = 1.f - gv;

#pragma unroll
  for (int j = 0; j < 4; ++j) {
    int c = cc * 32 + sg * 4 + j;
    int sbase2 = (sg * 4 + j) * 105 + chh * 13 + cw;
#define FWD_(o) float w##o = sde[sbase2 + ((o) / 5) * 13 + ((o) % 5)];
    REP25(FWD_)
    float s00 = 0.f, s01 = 0.f, s10 = 0.f, s11 = 0.f;
#define FCF_(o) { float4 kv = kled[(o)][cell]; \
                  s00 = fmaf(w##o, kv.x, s00); s01 = fmaf(w##o, kv.y, s01); \
                  s10 = fmaf(w##o, kv.z, s10); s11 = fmaf(w##o, kv.w, s11); }
    REP25(FCF_)

    const float* ep = en + ((size_t)(b * CHN + c) * HO + 2 * h) * WO + 2 * w;
    float* op = out + ((size_t)(b * CHN + c) * HO + 2 * h) * WO + 2 * w;
    float2 e0 = *(const float2*)(ep);
    float2 e1 = *(const float2*)(ep + WO);
    float2 r0, r1;
    r0.x = fmaf(gv, e0.x, gv1 * s00);
    r0.y = fmaf(gv, e0.y, gv1 * s01);
    r1.x = fmaf(gv, e1.x, gv1 * s10);
    r1.y = fmaf(gv, e1.y, gv1 * s11);
    *(float2*)(op) = r0;
    *(float2*)(op + WO) = r1;
  }
}

// ---------------------------------------------------------------------------
extern "C" void kernel_launch(void* const* d_in, const int* in_sizes, int n_in,
                              void* d_out, int out_size, void* d_ws, size_t ws_size,
                              hipStream_t stream) {
  const float* en      = (const float*)d_in[0];
  const float* de      = (const float*)d_in[1];
  const float* gate_w  = (const float*)d_in[2];
  const float* gate_b  = (const float*)d_in[3];
  const float* w1_en   = (const float*)d_in[4];
  const float* b1_en   = (const float*)d_in[5];
  const float* w1_de   = (const float*)d_in[6];
  const float* conv2_k = (const float*)d_in[7];
  const float* conv2_b = (const float*)d_in[8];
  float* ws  = (float*)d_ws;
  float* out = (float*)d_out;

  const unsigned short* bfu  = (const unsigned short*)(ws + OFF_WT_EN);
  const unsigned short* bfdu = (const unsigned short*)(ws + OFF_WT_DE);
  float* wc    = ws + OFF_WC;
  float* cesb  = ws + OFF_CES;
  float* cdgb  = ws + OFF_CDG;
  float* gateo = ws + OFF_GATE;
  float* kernb = ws + OFF_KERN;

  hipLaunchKernelGGL(fade_prep,   dim3(322),  dim3(256), 0, stream,
                     w1_en, w1_de, gate_w, conv2_k, ws, cesb, cdgb);
  hipLaunchKernelGGL(fade_conv1,  dim3(1000), dim3(256), 0, stream,
                     en, b1_en, bfu, cesb, de, gate_b, bfdu, cdgb, gateo);
  hipLaunchKernelGGL(fade_kern,   dim3(800),  dim3(512), 0, stream,
                     wc, cesb, cdgb, conv2_b, kernb);
  hipLaunchKernelGGL(fade_final,  dim3(3200), dim3(256), 0, stream,
                     en, de, kernb, gateo, out);
}

// Round 27
// 90.748 us; speedup vs baseline: 1.0874x; 1.0182x over previous
//
#include <hip/hip_runtime.h>
#include <hip/hip_bf16.h>

// Problem constants
constexpr int BB  = 2;
constexpr int CHN = 256;
constexpr int HH  = 80;
constexpr int WW  = 80;
constexpr int EE  = 64;
constexpr int HO  = 160;
constexpr int WO  = 160;

// Workspace layout (float offsets)
constexpr int OFF_WT_EN = 0;                    // BF bf16 B-frags of w1_en (16384 ushort)
constexpr int OFF_WT_DE = 16384;                // BF_DE bf16 B-frags of w1_de (16384 ushort) + BG gate frags (4096 ushort)
constexpr int OFF_WC    = 32768;                // BW bf16 B-frags of conv2_k (18432 ushort)
constexpr int OFF_CES   = 47168;                // [B][4][162][162][16] padded+scrambled ce
constexpr int CES_SZ    = 2 * 4 * 162 * 162 * 16;   // 3,359,232
constexpr int OFF_CDG   = OFF_CES + CES_SZ;     // [B][82][82][64] padded cd
constexpr int CDG_SZ    = 2 * 82 * 82 * 64;     // 860,672
constexpr int OFF_GATE  = OFF_CDG + CDG_SZ;     // [B][80][80]
constexpr int OFF_KERN  = OFF_GATE + 2 * 80 * 80;   // [B][80][80][25][4] softmaxed (o-major, q-minor!)

using bf16x8 = __attribute__((ext_vector_type(8))) short;
using f32x4  = __attribute__((ext_vector_type(4))) float;

// X-macro: apply F to 0..24 (forces compile-time indices -> registers; rule #20)
#define REP25(F) F(0) F(1) F(2) F(3) F(4) F(5) F(6) F(7) F(8) F(9) F(10) F(11) \
                 F(12) F(13) F(14) F(15) F(16) F(17) F(18) F(19) F(20) F(21) F(22) F(23) F(24)

// ---------------------------------------------------------------------------
// prep (merged): all weight transforms + both pad-ring zero-fills.
//  - BF / BF_DE / BG: 1x1-conv MFMA fragments (r14/r24 wins)
//  - BW (r27): bf16 MFMA B-frags of conv2_k for the kern GEMM:
//      BW[(ks*2+tile)*64 + l][j] = bf16(conv2_k[(o*64+c)*9 + d]),
//      k = ks*32 + (l>>4)*8 + j, d = k>>6, c = k&63, o = tile*16 + (l&15),
//      zero for o >= 25.
// ---------------------------------------------------------------------------
__global__ __launch_bounds__(256) void fade_prep(
    const float* __restrict__ w1_en, const float* __restrict__ w1_de,
    const float* __restrict__ gate_w, const float* __restrict__ conv2_k,
    float* __restrict__ ws, float* __restrict__ ces, float* __restrict__ cdg) {
  int idx = blockIdx.x * 256 + threadIdx.x;
  if (idx < 16384) {
    int j = idx & 7, l = (idx >> 3) & 63, et = (idx >> 9) & 3, ks = idx >> 11;
    int cc = ks * 32 + (l >> 4) * 8 + j;
    int ee = et * 16 + (l & 15);
    unsigned u = __float_as_uint(w1_en[ee * CHN + cc]);
    u = (u + 0x7FFFu + ((u >> 16) & 1u)) >> 16;   // RNE to bf16
    ((unsigned short*)(ws + OFF_WT_EN))[idx] = (unsigned short)u;
    unsigned v = __float_as_uint(w1_de[ee * CHN + cc]);
    v = (v + 0x7FFFu + ((v >> 16) & 1u)) >> 16;
    ((unsigned short*)(ws + OFF_WT_DE))[idx] = (unsigned short)v;
  }
  if (idx < 4096) {
    // BG: gate fragment, col 0 = gate_w, other cols 0. ks = idx>>9 (0..7)
    int j = idx & 7, l = (idx >> 3) & 63, ks = idx >> 9;
    int cc = ks * 32 + (l >> 4) * 8 + j;
    unsigned short r = 0;
    if ((l & 15) == 0) {
      unsigned u = __float_as_uint(gate_w[cc]);
      u = (u + 0x7FFFu + ((u >> 16) & 1u)) >> 16;
      r = (unsigned short)u;
    }
    ((unsigned short*)(ws + OFF_WT_DE))[16384 + idx] = r;
  }
  if (idx < 18432) {
    // BW: kern GEMM weight fragments
    int j = idx & 7, l = (idx >> 3) & 63, tile = (idx >> 9) & 1, ks = idx >> 10;
    int k = ks * 32 + ((l >> 4) & 3) * 8 + j;
    int d = k >> 6, c = k & 63;
    int o = tile * 16 + (l & 15);
    unsigned short r = 0;
    if (o < 25) {
      unsigned u = __float_as_uint(conv2_k[(o * EE + c) * 9 + d]);
      u = (u + 0x7FFFu + ((u >> 16) & 1u)) >> 16;
      r = (unsigned short)u;
    }
    ((unsigned short*)(ws + OFF_WC))[idx] = r;
  }
  if (idx < 82432) {
    int e4 = idx & 3;
    int rest = idx >> 2;
    int posb = rest % 644;
    int rest2 = rest / 644;
    int q = rest2 & 3, b = rest2 >> 2;
    int yy, xx;
    if (posb < 162)      { yy = 0;   xx = posb; }
    else if (posb < 324) { yy = 161; xx = posb - 162; }
    else if (posb < 484) { xx = 0;   yy = posb - 324 + 1; }
    else                 { xx = 161; yy = posb - 484 + 1; }
    float4 z = make_float4(0.f, 0.f, 0.f, 0.f);
    *(float4*)(ces + ((((size_t)b * 4 + q) * 162 + yy) * 162 + xx) * 16 + e4 * 4) = z;
  }
  if (idx < 10368) {
    // cdg pad ring: 324 cells/batch x 16 float4
    int e4 = idx & 15;
    int rest = idx >> 4;
    int cell = rest % 324, b = rest / 324;
    int yy, xx;
    if (cell < 82)       { yy = 0;  xx = cell; }
    else if (cell < 164) { yy = 81; xx = cell - 82; }
    else if (cell < 244) { xx = 0;  yy = cell - 164 + 1; }
    else                 { xx = 81; yy = cell - 244 + 1; }
    float4 z = make_float4(0.f, 0.f, 0.f, 0.f);
    *(float4*)(cdg + (((size_t)b * 82 + yy) * 82 + xx) * 64 + e4 * 4) = z;
  }
}

// ---------------------------------------------------------------------------
// conv1 (r24 win): BOTH 1x1 convs via bf16 MFMA, double-buffered LDS staging.
//   blocks [0,800):    ce = 1x1(en) -> scrambled ce_s interior
//   blocks [800,1000): cd = 1x1(de) -> cdg interior, + gate via a 5th MFMA
// ---------------------------------------------------------------------------
__global__ __launch_bounds__(256) void fade_conv1(
    const float* __restrict__ en, const float* __restrict__ b1_en,
    const unsigned short* __restrict__ BFu, float* __restrict__ ces,
    const float* __restrict__ de, const float* __restrict__ gate_b,
    const unsigned short* __restrict__ BFDu,
    float* __restrict__ cdg, float* __restrict__ gateo) {
  __shared__ float buf[2][32][65];
  int bi = blockIdx.x;
  int tid = threadIdx.x;
  int lane = tid & 63;
  int w = __builtin_amdgcn_readfirstlane(tid >> 6);   // 0..3
  int l15 = lane & 15, lg = lane >> 4;
  int cg = tid >> 6, po = tid & 63;

  if (bi < 800) {
    // ---------------- en path ----------------
    int b = bi / 400;
    int pos0 = (bi % 400) * 64;       // within batch plane (25600)
    const float* ep = en + (size_t)b * CHN * 25600 + pos0;
    const bf16x8* BFF = (const bf16x8*)BFu;

    f32x4 acc0, acc1, acc2, acc3;
    { float bv = b1_en[l15];      acc0 = (f32x4){bv, bv, bv, bv}; }
    { float bv = b1_en[16 + l15]; acc1 = (f32x4){bv, bv, bv, bv}; }
    { float bv = b1_en[32 + l15]; acc2 = (f32x4){bv, bv, bv, bv}; }
    { float bv = b1_en[48 + l15]; acc3 = (f32x4){bv, bv, bv, bv}; }

#pragma unroll
    for (int i = 0; i < 8; ++i) {
      int c = i * 4 + cg;
      buf[0][c][po] = ep[(size_t)c * 25600 + po];
    }
    __syncthreads();

    for (int ks = 0; ks < 8; ++ks) {
      int p = ks & 1;
      if (ks < 7) {
#pragma unroll
        for (int i = 0; i < 8; ++i) {
          int c = i * 4 + cg;
          buf[p ^ 1][c][po] = ep[(size_t)((ks + 1) * 32 + c) * 25600 + po];
        }
      }
      bf16x8 av;
#define LDA_(j) { unsigned u = __float_as_uint(buf[p][lg * 8 + (j)][w * 16 + l15]); \
      u = (u + 0x7FFFu + ((u >> 16) & 1u)) >> 16; av[(j)] = (short)u; }
      LDA_(0) LDA_(1) LDA_(2) LDA_(3) LDA_(4) LDA_(5) LDA_(6) LDA_(7)
#undef LDA_
      const bf16x8* bp = BFF + ks * 256 + lane;
      bf16x8 b0 = bp[0], b1 = bp[64], b2 = bp[128], b3 = bp[192];
      acc0 = __builtin_amdgcn_mfma_f32_16x16x32_bf16(av, b0, acc0, 0, 0, 0);
      acc1 = __builtin_amdgcn_mfma_f32_16x16x32_bf16(av, b1, acc1, 0, 0, 0);
      acc2 = __builtin_amdgcn_mfma_f32_16x16x32_bf16(av, b2, acc2, 0, 0, 0);
      acc3 = __builtin_amdgcn_mfma_f32_16x16x32_bf16(av, b3, acc3, 0, 0, 0);
      __syncthreads();
    }

    constexpr size_t QSTR = (size_t)162 * 162 * 16;
    float* cb = ces + (size_t)b * 4 * QSTR;
    int pbase = pos0 + w * 16 + lg * 4;
    int q = l15 & 3;
#define WR_(r) { int p2 = pbase + (r); int y = p2 / 160, x = p2 - y * 160; \
      size_t sb = (size_t)q * QSTR + (size_t)((y + 1) * 162 + (x + 1)) * 16 + (l15 >> 2); \
      cb[sb +  0] = acc0[(r)]; \
      cb[sb +  4] = acc1[(r)]; \
      cb[sb +  8] = acc2[(r)]; \
      cb[sb + 12] = acc3[(r)]; }
    WR_(0) WR_(1) WR_(2) WR_(3)
#undef WR_
  } else {
    // ---------------- de path (MFMA + gate column) ----------------
    int bj = bi - 800;
    int b = bj / 100;
    int pos0 = (bj % 100) * 64;       // within de plane (6400)
    const float* dp = de + (size_t)b * CHN * 6400 + pos0;
    const bf16x8* BFD = (const bf16x8*)BFDu;
    const bf16x8* BG  = (const bf16x8*)(BFDu + 16384);

    f32x4 acc0 = {0.f, 0.f, 0.f, 0.f}, acc1 = acc0, acc2 = acc0, acc3 = acc0;
    f32x4 accg;
    { float gb = gate_b[0]; accg = (f32x4){gb, gb, gb, gb}; }

#pragma unroll
    for (int i = 0; i < 8; ++i) {
      int c = i * 4 + cg;
      buf[0][c][po] = dp[(size_t)c * 6400 + po];
    }
    __syncthreads();

    for (int ks = 0; ks < 8; ++ks) {
      int p = ks & 1;
      if (ks < 7) {
#pragma unroll
        for (int i = 0; i < 8; ++i) {
          int c = i * 4 + cg;
          buf[p ^ 1][c][po] = dp[(size_t)((ks + 1) * 32 + c) * 6400 + po];
        }
      }
      bf16x8 av;
#define LDB_(j) { unsigned u = __float_as_uint(buf[p][lg * 8 + (j)][w * 16 + l15]); \
      u = (u + 0x7FFFu + ((u >> 16) & 1u)) >> 16; av[(j)] = (short)u; }
      LDB_(0) LDB_(1) LDB_(2) LDB_(3) LDB_(4) LDB_(5) LDB_(6) LDB_(7)
#undef LDB_
      const bf16x8* bp = BFD + ks * 256 + lane;
      bf16x8 b0 = bp[0], b1 = bp[64], b2 = bp[128], b3 = bp[192];
      bf16x8 bg = BG[ks * 64 + lane];
      acc0 = __builtin_amdgcn_mfma_f32_16x16x32_bf16(av, b0, acc0, 0, 0, 0);
      acc1 = __builtin_amdgcn_mfma_f32_16x16x32_bf16(av, b1, acc1, 0, 0, 0);
      acc2 = __builtin_amdgcn_mfma_f32_16x16x32_bf16(av, b2, acc2, 0, 0, 0);
      acc3 = __builtin_amdgcn_mfma_f32_16x16x32_bf16(av, b3, acc3, 0, 0, 0);
      accg = __builtin_amdgcn_mfma_f32_16x16x32_bf16(av, bg, accg, 0, 0, 0);
      __syncthreads();
    }

    float* cdb = cdg + (size_t)b * 82 * 82 * 64;
    int pbase = pos0 + w * 16 + lg * 4;
#define WRD_(r) { int p2 = pbase + (r); int y = p2 / 80, x = p2 - y * 80; \
      size_t sb = (size_t)((y + 1) * 82 + (x + 1)) * 64 + l15; \
      cdb[sb +  0] = acc0[(r)]; \
      cdb[sb + 16] = acc1[(r)]; \
      cdb[sb + 32] = acc2[(r)]; \
      cdb[sb + 48] = acc3[(r)]; \
      if (l15 == 0) gateo[(size_t)b * 6400 + p2] = 1.f / (1.f + __expf(-accg[(r)])); }
    WRD_(0) WRD_(1) WRD_(2) WRD_(3)
#undef WRD_
  }
}

// ---------------------------------------------------------------------------
// kern (r27): tap-conv as bf16 MFMA GEMM. score[pos][o] = sum_k (u+v)*W,
// M = 51200 rows (pos = b,q,h,w), N = 32 (25 used), K = 576 (9 taps x 64 ch).
// Block = 256 thr = 4 waves; wave = 16 rows x full K (18 steps of 32).
// Per step each lane gathers the SAME 4 float4 (CDG pair + CES pair) the
// old kern loaded, sums u+v, cvt->bf16 (A row=l15, k=lg*8+j -- the exact
// lane mapping proven in conv1a), then 2 MFMAs vs BW o-tiles.
// Softmax cross-lane: lane holds rows lg*4+r, cols o=l15 / 16+l15;
// reduce over 16 o-columns via __shfl_xor(width 16). Zero LDS.
// Replaces 1800 VALU FMAs/thread with 36 MFMAs/wave (old: 30us @ 40% VALU).
// ---------------------------------------------------------------------------
__global__ __launch_bounds__(256) void fade_kern(
    const unsigned short* __restrict__ BWu, const float* __restrict__ CES,
    const float* __restrict__ CDG, const float* __restrict__ conv2_b,
    float* __restrict__ KERN) {
  int bi = blockIdx.x;
  int b = bi / 400, t = bi % 400;
  int th0 = (t / 20) * 4, tw0 = (t % 20) * 4;
  int tid = threadIdx.x;
  int lane = tid & 63;
  int wt = __builtin_amdgcn_readfirstlane(tid >> 6);   // row-tile 0..3
  int l15 = lane & 15, lg = lane >> 4;

  // A-side row for this lane: row = wt*16 + l15 -> (cell, q)
  int arow = wt * 16 + l15;
  int acell = arow >> 2, aq = arow & 3;
  int ah = th0 + (acell >> 2), aw = tw0 + (acell & 3);

  const bf16x8* BW = (const bf16x8*)BWu;

  f32x4 acc0 = {0.f, 0.f, 0.f, 0.f}, acc1 = acc0;

  const float* cdg_base = CDG + (((size_t)b * 82 + ah) * 82 + aw) * 64;
  const float* ces_qbase = CES + ((size_t)b * 4 + aq) * ((size_t)162 * 162 * 16);

  for (int ks = 0; ks < 18; ++ks) {
    int d = ks >> 1;                            // wave-uniform tap
    int di = d / 3, dj = d - 3 * di;
    int c0 = (ks & 1) * 32 + lg * 8;            // per-lane channel offset
    int g = c0 >> 4;                            // pad group 0..3
    int pt = (g < 2) ? 1 : 0;
    int pl = (g & 1) ? 0 : 1;
    int eb = c0 & 8;
    const float* cpd = cdg_base + (di * 82 + dj) * 64 + c0;
    const float* cpe = ces_qbase +
        (size_t)((2 * ah + di - pt + 1) * 162 + (2 * aw + dj - pl + 1)) * 16 + eb;
    float4 u0 = *(const float4*)(cpd);
    float4 u1 = *(const float4*)(cpd + 4);
    float4 v0 = *(const float4*)(cpe);
    float4 v1 = *(const float4*)(cpe + 4);
    float s0 = u0.x + v0.x, s1 = u0.y + v0.y, s2 = u0.z + v0.z, s3 = u0.w + v0.w;
    float s4 = u1.x + v1.x, s5 = u1.y + v1.y, s6 = u1.z + v1.z, s7 = u1.w + v1.w;
    bf16x8 av;
#define CVT_(j, sv) { unsigned uu = __float_as_uint(sv); \
    uu = (uu + 0x7FFFu + ((uu >> 16) & 1u)) >> 16; av[(j)] = (short)uu; }
    CVT_(0, s0) CVT_(1, s1) CVT_(2, s2) CVT_(3, s3)
    CVT_(4, s4) CVT_(5, s5) CVT_(6, s6) CVT_(7, s7)
#undef CVT_
    bf16x8 b0 = BW[(ks * 2 + 0) * 64 + lane];
    bf16x8 b1 = BW[(ks * 2 + 1) * 64 + lane];
    acc0 = __builtin_amdgcn_mfma_f32_16x16x32_bf16(av, b0, acc0, 0, 0, 0);
    acc1 = __builtin_amdgcn_mfma_f32_16x16x32_bf16(av, b1, acc1, 0, 0, 0);
  }

  // softmax over o (cross-lane within 16-lane groups) + write
  float bo0 = 2.f * conv2_b[l15];                     // bias appears in BOTH convs
  float bo1 = (l15 < 9) ? 2.f * conv2_b[16 + l15] : 0.f;
#pragma unroll
  for (int r = 0; r < 4; ++r) {
    int grow = wt * 16 + lg * 4 + r;                  // D-row -> (cell, q)
    int cell = grow >> 2, q = grow & 3;
    int h = th0 + (cell >> 2), w = tw0 + (cell & 3);
    float sc0 = acc0[r] + bo0;
    float sc1 = (l15 < 9) ? (acc1[r] + bo1) : -1e30f;
    float m = fmaxf(sc0, sc1);
#pragma unroll
    for (int mk = 1; mk < 16; mk <<= 1)
      m = fmaxf(m, __shfl_xor(m, mk, 16));
    float e0 = __expf(sc0 - m);
    float e1 = (l15 < 9) ? __expf(sc1 - m) : 0.f;
    float sm = e0 + e1;
#pragma unroll
    for (int mk = 1; mk < 16; mk <<= 1)
      sm += __shfl_xor(sm, mk, 16);
    float inv = 1.f / sm;
    float* kp = KERN + (size_t)(b * 6400 + h * 80 + w) * 100 + q;
    kp[l15 * 4] = e0 * inv;
    if (l15 < 9) kp[(16 + l15) * 4] = e1 * inv;
  }
}

// ---------------------------------------------------------------------------
// final: CARAFE + gate blend, EXACT r24 structure (grid 3200, LDS staging).
// ---------------------------------------------------------------------------
__global__ __launch_bounds__(256) void fade_final(
    const float* __restrict__ en, const float* __restrict__ de,
    const float* __restrict__ KERN, const float* __restrict__ GATE,
    float* __restrict__ out) {
  __shared__ float sde[32 * 105];    // 32 channels x (8 rows x 13 cols pad)
  __shared__ float4 kled[25][33];    // [o][cell], pad 33 vs write conflicts
  int bi = blockIdx.x;
  int b = bi / 1600, r = bi % 1600;
  int t = r >> 3, cc = r & 7;
  int th0 = (t / 10) * 4, tw0 = (t % 10) * 8;
  int tid = threadIdx.x;
  int sg = tid >> 5, cell = tid & 31;
  int chh = cell >> 3, cw = cell & 7;
  int h = th0 + chh, w = tw0 + cw;

  // stage de: channels cc*32 .. +32, rows th0-2..+5, cols tw0-2..+9
  for (int kk = tid; kk < 3072; kk += 256) {
    int ci = kk / 96, rem = kk % 96, rr = rem / 12, c2 = rem % 12;
    int dr = th0 - 2 + rr, dc = tw0 - 2 + c2;
    float v = 0.f;
    if (dr >= 0 && dr < HH && dc >= 0 && dc < WW)
      v = de[((size_t)(b * CHN + cc * 32 + ci) * HH + dr) * WW + dc];
    sde[ci * 105 + rr * 13 + c2] = v;
  }
  // stage kern: 800 float4 (32 cells x 25 o), coalesced (o fastest)
  for (int kk = tid; kk < 800; kk += 256) {
    int cl2 = kk / 25, o = kk % 25;
    int hc = th0 + (cl2 >> 3), wc = tw0 + (cl2 & 7);
    kled[o][cl2] = *((const float4*)(KERN + (size_t)(b * 6400 + hc * 80 + wc) * 100) + o);
  }
  __syncthreads();

  float gv = GATE[((size_t)b * 80 + h) * 80 + w];
  float gv1 = 1.f - gv;

#pragma unroll
  for (int j = 0; j < 4; ++j) {
    int c = cc * 32 + sg * 4 + j;
    int sbase2 = (sg * 4 + j) * 105 + chh * 13 + cw;
#define FWD_(o) float w##o = sde[sbase2 + ((o) / 5) * 13 + ((o) % 5)];
    REP25(FWD_)
    float s00 = 0.f, s01 = 0.f, s10 = 0.f, s11 = 0.f;
#define FCF_(o) { float4 kv = kled[(o)][cell]; \
                  s00 = fmaf(w##o, kv.x, s00); s01 = fmaf(w##o, kv.y, s01); \
                  s10 = fmaf(w##o, kv.z, s10); s11 = fmaf(w##o, kv.w, s11); }
    REP25(FCF_)

    const float* ep = en + ((size_t)(b * CHN + c) * HO + 2 * h) * WO + 2 * w;
    float* op = out + ((size_t)(b * CHN + c) * HO + 2 * h) * WO + 2 * w;
    float2 e0 = *(const float2*)(ep);
    float2 e1 = *(const float2*)(ep + WO);
    float2 r0, r1;
    r0.x = fmaf(gv, e0.x, gv1 * s00);
    r0.y = fmaf(gv, e0.y, gv1 * s01);
    r1.x = fmaf(gv, e1.x, gv1 * s10);
    r1.y = fmaf(gv, e1.y, gv1 * s11);
    *(float2*)(op) = r0;
    *(float2*)(op + WO) = r1;
  }
}

// ---------------------------------------------------------------------------
extern "C" void kernel_launch(void* const* d_in, const int* in_sizes, int n_in,
                              void* d_out, int out_size, void* d_ws, size_t ws_size,
                              hipStream_t stream) {
  const float* en      = (const float*)d_in[0];
  const float* de      = (const float*)d_in[1];
  const float* gate_w  = (const float*)d_in[2];
  const float* gate_b  = (const float*)d_in[3];
  const float* w1_en   = (const float*)d_in[4];
  const float* b1_en   = (const float*)d_in[5];
  const float* w1_de   = (const float*)d_in[6];
  const float* conv2_k = (const float*)d_in[7];
  const float* conv2_b = (const float*)d_in[8];
  float* ws  = (float*)d_ws;
  float* out = (float*)d_out;

  const unsigned short* bfu  = (const unsigned short*)(ws + OFF_WT_EN);
  const unsigned short* bfdu = (const unsigned short*)(ws + OFF_WT_DE);
  const unsigned short* bwu  = (const unsigned short*)(ws + OFF_WC);
  float* cesb  = ws + OFF_CES;
  float* cdgb  = ws + OFF_CDG;
  float* gateo = ws + OFF_GATE;
  float* kernb = ws + OFF_KERN;

  hipLaunchKernelGGL(fade_prep,   dim3(322),  dim3(256), 0, stream,
                     w1_en, w1_de, gate_w, conv2_k, ws, cesb, cdgb);
  hipLaunchKernelGGL(fade_conv1,  dim3(1000), dim3(256), 0, stream,
                     en, b1_en, bfu, cesb, de, gate_b, bfdu, cdgb, gateo);
  hipLaunchKernelGGL(fade_kern,   dim3(800),  dim3(256), 0, stream,
                     bwu, cesb, cdgb, conv2_b, kernb);
  hipLaunchKernelGGL(fade_final,  dim3(3200), dim3(256), 0, stream,
                     en, de, kernb, gateo, out);
}